// Round 13
// baseline (12748.732 us; speedup 1.0000x reference)
//
#include <hip/hip_runtime.h>

typedef float f32x2 __attribute__((ext_vector_type(2)));
typedef float f32x4 __attribute__((ext_vector_type(4)));
typedef short bf16x8 __attribute__((ext_vector_type(8)));
typedef _Float16 f16x2 __attribute__((ext_vector_type(2)));
typedef _Float16 f16x4 __attribute__((ext_vector_type(4)));
typedef _Float16 f16x8 __attribute__((ext_vector_type(8)));

#define SEQ 2048
#define HD 2048
#define NG 8192
#define KD 2048
#define NB 256
#define NT 512
#define PAD_CH 136                    // fp16 per 128-elem h-chunk incl. 8 pad (272B stride)

__device__ __forceinline__ unsigned short f32_to_bf16_rne(float f) {
    unsigned int u = __float_as_uint(f);
    u += 0x7FFFu + ((u >> 16) & 1u);
    return (unsigned short)(u >> 16);
}

__global__ void cvt_f16_kernel(const float* __restrict__ in, _Float16* __restrict__ out, int n) {
    for (int i = blockIdx.x * blockDim.x + threadIdx.x; i < n; i += gridDim.x * blockDim.x)
        out[i] = (_Float16)in[i];
}

// ---------------- GEMM: xg[s][g] = sum_k x[s][k] * w_ih[g][k] + b_ih[g] + b_hh[g] ----------------
__global__ __launch_bounds__(256) void gemm_xg(
    const float* __restrict__ A,    // x   [2048][2048]
    const float* __restrict__ B,    // w_ih[8192][2048]
    const float* __restrict__ bih, const float* __restrict__ bhh,
    float* __restrict__ C)          // xg  [2048][8192]
{
    __shared__ unsigned short As[128 * 32];
    __shared__ unsigned short Bs[128 * 32];
    const int tid = threadIdx.x;
    const int bm = blockIdx.x, bn = blockIdx.y;
    const int wave = tid >> 6, lane = tid & 63;
    const int wr = wave >> 1, wc = wave & 1;
    const int l15 = lane & 15, l4 = lane >> 4;

    f32x4 acc[4][4];
    #pragma unroll
    for (int i = 0; i < 4; ++i)
        #pragma unroll
        for (int j = 0; j < 4; ++j) {
            f32x4 z = {0.f, 0.f, 0.f, 0.f};
            acc[i][j] = z;
        }

    for (int k0 = 0; k0 < KD; k0 += 32) {
        #pragma unroll
        for (int i = 0; i < 2; ++i) {
            int idx = tid + i * 256;
            int row = idx >> 2, c8 = idx & 3;
            const float* ga = A + (size_t)(bm * 128 + row) * KD + k0 + c8 * 8;
            float4 a0 = *(const float4*)ga;
            float4 a1 = *(const float4*)(ga + 4);
            bf16x8 av;
            av[0] = (short)f32_to_bf16_rne(a0.x); av[1] = (short)f32_to_bf16_rne(a0.y);
            av[2] = (short)f32_to_bf16_rne(a0.z); av[3] = (short)f32_to_bf16_rne(a0.w);
            av[4] = (short)f32_to_bf16_rne(a1.x); av[5] = (short)f32_to_bf16_rne(a1.y);
            av[6] = (short)f32_to_bf16_rne(a1.z); av[7] = (short)f32_to_bf16_rne(a1.w);
            *(bf16x8*)&As[row * 32 + c8 * 8] = av;
            const float* gb = B + (size_t)(bn * 128 + row) * KD + k0 + c8 * 8;
            float4 b0 = *(const float4*)gb;
            float4 b1 = *(const float4*)(gb + 4);
            bf16x8 bv;
            bv[0] = (short)f32_to_bf16_rne(b0.x); bv[1] = (short)f32_to_bf16_rne(b0.y);
            bv[2] = (short)f32_to_bf16_rne(b0.z); bv[3] = (short)f32_to_bf16_rne(b0.w);
            bv[4] = (short)f32_to_bf16_rne(b1.x); bv[5] = (short)f32_to_bf16_rne(b1.y);
            bv[6] = (short)f32_to_bf16_rne(b1.z); bv[7] = (short)f32_to_bf16_rne(b1.w);
            *(bf16x8*)&Bs[row * 32 + c8 * 8] = bv;
        }
        __syncthreads();
        bf16x8 af[4], bfr[4];
        #pragma unroll
        for (int m = 0; m < 4; ++m) af[m] = *(const bf16x8*)&As[(wr * 64 + m * 16 + l15) * 32 + l4 * 8];
        #pragma unroll
        for (int n = 0; n < 4; ++n) bfr[n] = *(const bf16x8*)&Bs[(wc * 64 + n * 16 + l15) * 32 + l4 * 8];
        #pragma unroll
        for (int m = 0; m < 4; ++m)
            #pragma unroll
            for (int n = 0; n < 4; ++n)
                acc[m][n] = __builtin_amdgcn_mfma_f32_16x16x32_bf16(af[m], bfr[n], acc[m][n], 0, 0, 0);
        __syncthreads();
    }
    #pragma unroll
    for (int m = 0; m < 4; ++m) {
        #pragma unroll
        for (int n = 0; n < 4; ++n) {
            int col = bn * 128 + wc * 64 + n * 16 + l15;
            float bias = bih[col] + bhh[col];
            int row0 = bm * 128 + wr * 64 + m * 16 + l4 * 4;
            #pragma unroll
            for (int r = 0; r < 4; ++r)
                C[(size_t)(row0 + r) * NG + col] = acc[m][n][r] + bias;
        }
    }
}

// ---- LLC-coherent primitives (agent scope; no cache-wide fences anywhere) ----
__device__ __forceinline__ void st_llc16(float* p, f32x4 v) {
    asm volatile("global_store_dwordx4 %0, %1, off sc0 sc1" :: "v"(p), "v"(v) : "memory");
}
__device__ __forceinline__ void st_llc8(float* p, f32x2 v) {
    asm volatile("global_store_dwordx2 %0, %1, off sc0 sc1" :: "v"(p), "v"(v) : "memory");
}
// issue 4 coherent 16B partial loads at p+0/16/32/48, NO wait
__device__ __forceinline__ void ld_llc_issue_p(const float* p, f32x4& a, f32x4& b, f32x4& c, f32x4& d) {
    asm volatile(
        "global_load_dwordx4 %0, %4, off sc0 sc1\n\t"
        "global_load_dwordx4 %1, %4, off offset:16 sc0 sc1\n\t"
        "global_load_dwordx4 %2, %4, off offset:32 sc0 sc1\n\t"
        "global_load_dwordx4 %3, %4, off offset:48 sc0 sc1"
        : "=&v"(a), "=&v"(b), "=&v"(c), "=&v"(d)
        : "v"(p)
        : "memory");
}
// issue 4 coherent 16B gate loads, NO wait
__device__ __forceinline__ void ld_llc_issue4(const float* p0, const float* p1,
                                              const float* p2, const float* p3,
                                              f32x4& a, f32x4& b, f32x4& c, f32x4& d) {
    asm volatile(
        "global_load_dwordx4 %0, %4, off sc0 sc1\n\t"
        "global_load_dwordx4 %1, %5, off sc0 sc1\n\t"
        "global_load_dwordx4 %2, %6, off sc0 sc1\n\t"
        "global_load_dwordx4 %3, %7, off sc0 sc1"
        : "=&v"(a), "=&v"(b), "=&v"(c), "=&v"(d)
        : "v"(p0), "v"(p1), "v"(p2), "v"(p3)
        : "memory");
}
// untracked plain 16B load (xg prefetch; normal caching, issued LAST)
__device__ __forceinline__ void ld_gl16(const float* p, f32x4& a) {
    asm volatile("global_load_dwordx4 %0, %1, off" : "=&v"(a) : "v"(p) : "memory");
}
// counted waits (issue order per wave: [y] [partials x4] gq x4, xg) — xg ALWAYS newest
__device__ __forceinline__ void wait_vm5(f32x4& a, f32x4& b, f32x4& c, f32x4& d) {
    asm volatile("s_waitcnt vmcnt(5)" : "+v"(a), "+v"(b), "+v"(c), "+v"(d) :: "memory");
    __builtin_amdgcn_sched_barrier(0);
}
__device__ __forceinline__ void wait_vm1(f32x4& a, f32x4& b, f32x4& c, f32x4& d) {
    asm volatile("s_waitcnt vmcnt(1)" : "+v"(a), "+v"(b), "+v"(c), "+v"(d) :: "memory");
    __builtin_amdgcn_sched_barrier(0);
}
__device__ __forceinline__ void wait_vm0_1(f32x4& a) {
    asm volatile("s_waitcnt vmcnt(0)" : "+v"(a) :: "memory");
    __builtin_amdgcn_sched_barrier(0);
}

__device__ __forceinline__ float rcpf(float x) { return __builtin_amdgcn_rcpf(x); }
__device__ __forceinline__ float rsqf(float x) { return __builtin_amdgcn_rsqf(x); }
__device__ __forceinline__ float sigf(float x) { return rcpf(1.0f + __expf(-x)); }
__device__ __forceinline__ float tanhfast(float x) {
    float ax = fabsf(x);
    float e = __expf(-2.0f * ax);
    return __builtin_copysignf((1.0f - e) * rcpf(1.0f + e), x);
}

// intra-block barrier draining ONLY LDS (lgkm) — leaves global loads in flight
__device__ __forceinline__ void bar_lgkm() {
    asm volatile("s_waitcnt lgkmcnt(0)" ::: "memory");
    __builtin_amdgcn_s_barrier();
}

// barctl layout (unsigned, 64-word = 256B spacing):
//   [l*64]      l=0..63  per-wave-group arrival counters (32 waves each; RMW only)
//   [(64+l)*64] l=0..63  done lines (write-once per step; poll targets)
// Poll targets DISJOINT from RMW targets — load-bearing (R8: polling the
// counters serialized arrivals behind the reader storm, 2x regression).
#define DONE_OFF (64 * 64)

// ---------------- Persistent recurrence: per-wave arrival barrier per step ----------------
__global__ __launch_bounds__(512, 2) void lstm_rec(
    const float* __restrict__ xg,          // [SEQ][NG]
    const _Float16* __restrict__ Whh,      // [NG][HD] fp16
    const float* __restrict__ gamma,       // [5][HD]
    const float* __restrict__ beta,        // [5][HD]
    float* __restrict__ gates,             // [2][NG] f32, double-buffered
    float* __restrict__ partials,          // [2][NB*8*2] f32 {s,q} per (block,wave), dbuffered
    unsigned* __restrict__ barctl,
    float* __restrict__ yout)              // y[SEQ][HD], hy[HD], cy[HD]
{
    __shared__ _Float16 hlds[16 * PAD_CH];
    __shared__ __align__(16) float red2[16];    // cy partials [s: w | q: 8+w]
    __shared__ __align__(16) float statsmem[8]; // 4 gates x {m, r}

    const int b = blockIdx.x;
    const int t = threadIdx.x;
    const int wave = t >> 6, lane = t & 63;
    const int p = t * 4;                   // this thread's 4 H-positions

    const int wline = (b * 8 + wave) >> 5; // 0..63 (4 blocks' waves per line)
    unsigned* arrcnt = barctl + wline * 64;

    const int row = t >> 4, sub = t & 15;  // GEMV: row 0..31, 128-col chunk
    const int grow = b * 32 + row;
    const bool owner = ((t >> 1) == b);    // threads 2b,2b+1 own y-slice [8b,8b+8)

    // ---- W strip -> 64 VGPRs (one-time) ----
    f16x8 wreg[16];
    {
        const _Float16* wsrc = Whh + (size_t)grow * HD + sub * 128;
        #pragma unroll
        for (int i = 0; i < 16; ++i) wreg[i] = *(const f16x8*)(wsrc + i * 8);
    }
    for (int k = t; k < 16 * PAD_CH; k += NT) hlds[k] = (_Float16)0.0f;

    float4 gm[4], bt[4];
    #pragma unroll
    for (int g = 0; g < 4; ++g) {
        gm[g] = *(const float4*)&gamma[g * HD + p];
        bt[g] = *(const float4*)&beta[g * HD + p];
    }
    float4 gm4 = *(const float4*)&gamma[4 * HD + p];
    float4 bt4 = *(const float4*)&beta[4 * HD + p];

    float* hyout = yout + (size_t)SEQ * HD;
    float* cyout = hyout + HD;
    const float invH = 1.0f / 2048.0f;

    float cprev[4] = {0.f, 0.f, 0.f, 0.f};
    float4 prevy = {0.f, 0.f, 0.f, 0.f};  // previous step's h slice (owner writes post-release)
    float4 prevc = {0.f, 0.f, 0.f, 0.f};

    // lane0 of wave w holds xg f32x4 for rows b*32 + 4w .. +3
    f32x4 xg4 = {0.f, 0.f, 0.f, 0.f};
    if (lane == 0) xg4 = *(const f32x4*)(xg + b * 32 + wave * 4);

    const _Float16* hch = hlds + sub * PAD_CH;
    __syncthreads();

    for (int step = 0; step < SEQ; ++step) {
        float* gb = gates + (size_t)(step & 1) * NG;
        float* pb = partials + (size_t)(step & 1) * (NB * 8 * 2);
        const unsigned gen = (unsigned)(step + 1);

        // retire xg prefetch (+ any old y-store ack) before use
        wait_vm0_1(xg4);

        // ---------- GEMV from registers; h via LDS broadcast ----------
        float accv[4] = {0.f, 0.f, 0.f, 0.f};
        #pragma unroll
        for (int i = 0; i < 16; ++i) {
            f16x8 hv = *(const f16x8*)(hch + i * 8);
            const f16x2* w2 = (const f16x2*)&wreg[i];
            const f16x2* h2 = (const f16x2*)&hv;
            float x = accv[i & 3];
            x = __builtin_amdgcn_fdot2(w2[0], h2[0], x, false);
            x = __builtin_amdgcn_fdot2(w2[1], h2[1], x, false);
            x = __builtin_amdgcn_fdot2(w2[2], h2[2], x, false);
            x = __builtin_amdgcn_fdot2(w2[3], h2[3], x, false);
            accv[i & 3] = x;
        }
        float r = (accv[0] + accv[1]) + (accv[2] + accv[3]);
        #pragma unroll
        for (int off = 1; off < 16; off <<= 1) r += __shfl_xor(r, off);
        float r1 = __shfl(r, 16), r2 = __shfl(r, 32), r3 = __shfl(r, 48);
        if (lane == 0) {
            float g0 = r + xg4[0], g1 = r1 + xg4[1], g2 = r2 + xg4[2], g3 = r3 + xg4[3];
            f32x4 gv4 = {g0, g1, g2, g3};
            st_llc16(&gb[b * 32 + wave * 4], gv4);
            f32x2 pq = {(g0 + g1) + (g2 + g3),
                        (g0 * g0 + g1 * g1) + (g2 * g2 + g3 * g3)};
            st_llc8(&pb[(b * 8 + wave) * 2], pq);
        }

        // ---------- per-wave arrival: own-drain then add; completer writes done line ----------
        asm volatile("s_waitcnt vmcnt(0)" ::: "memory");   // this wave's stores at LLC
        if (lane == 0) {
            unsigned o1 = __hip_atomic_fetch_add(arrcnt, 1u, __ATOMIC_RELAXED, __HIP_MEMORY_SCOPE_AGENT);
            if (o1 == gen * 32u - 1u)
                __hip_atomic_store(barctl + DONE_OFF + wline * 64, gen,
                                   __ATOMIC_RELAXED, __HIP_MEMORY_SCOPE_AGENT);
        }
        // ---------- release: every lane polls one of the 64 write-once done lines ----------
        for (;;) {
            unsigned v = __hip_atomic_load(barctl + DONE_OFF + lane * 64,
                                           __ATOMIC_RELAXED, __HIP_MEMORY_SCOPE_AGENT);
            if (__all(v >= gen)) break;
            __builtin_amdgcn_s_sleep(1);
        }
        asm volatile("" ::: "memory");

        // ---------- post-release: y-store (prev step), then counted-vmcnt loads ----------
        if (step > 0 && owner)
            *(float4*)&yout[(size_t)(step - 1) * HD + p] = prevy;

        f32x4 pa, pbv, pc, pd;
        if (wave < 4)
            ld_llc_issue_p(&pb[wave * 1024 + lane * 16], pa, pbv, pc, pd);
        f32x4 gq[4];
        ld_llc_issue4(&gb[0 * HD + p], &gb[1 * HD + p], &gb[2 * HD + p], &gb[3 * HD + p],
                      gq[0], gq[1], gq[2], gq[3]);
        if (lane == 0)   // unconditional (modular) -> vmcnt counts identical every step
            ld_gl16(xg + (size_t)((step + 1) & (SEQ - 1)) * NG + b * 32 + wave * 4, xg4);

        // waves 0-3: stats from partials; waits only the oldest 5 ([y]+partials)
        if (wave < 4) {
            wait_vm5(pa, pbv, pc, pd);
            float s = ((pa[0] + pa[2]) + (pbv[0] + pbv[2])) + ((pc[0] + pc[2]) + (pd[0] + pd[2]));
            float q = ((pa[1] + pa[3]) + (pbv[1] + pbv[3])) + ((pc[1] + pc[3]) + (pd[1] + pd[3]));
            #pragma unroll
            for (int off = 1; off < 64; off <<= 1) { s += __shfl_xor(s, off); q += __shfl_xor(q, off); }
            if (lane == 0) {
                float m = s * invH;
                statsmem[wave * 2] = m;
                statsmem[wave * 2 + 1] = rsqf(q * invH - m * m + 1e-5f);
            }
        }
        bar_lgkm();   // [A] stats visible (lgkm only: gq+xg stay in flight)

        wait_vm1(gq[0], gq[1], gq[2], gq[3]);   // gq ready; xg remains in flight
        float mg[4], rg[4];
        {
            const f32x4* sm = (const f32x4*)statsmem;
            f32x4 s0 = sm[0], s1 = sm[1];
            mg[0] = s0[0]; rg[0] = s0[1]; mg[1] = s0[2]; rg[1] = s0[3];
            mg[2] = s1[0]; rg[2] = s1[1]; mg[3] = s1[2]; rg[3] = s1[3];
        }

        float rcv[4], og4[4];
        float s2 = 0.f, q2 = 0.f;
        #pragma unroll
        for (int j = 0; j < 4; ++j) {
            float li = (gq[0][j] - mg[0]) * rg[0] * ((const float*)&gm[0])[j] + ((const float*)&bt[0])[j];
            float lf = (gq[1][j] - mg[1]) * rg[1] * ((const float*)&gm[1])[j] + ((const float*)&bt[1])[j];
            float lg = (gq[2][j] - mg[2]) * rg[2] * ((const float*)&gm[2])[j] + ((const float*)&bt[2])[j];
            float lo = (gq[3][j] - mg[3]) * rg[3] * ((const float*)&gm[3])[j] + ((const float*)&bt[3])[j];
            float ig = sigf(li);
            float fg = sigf(lf);
            float gg = tanhfast(lg);
            float og = sigf(lo);
            float rv = fg * cprev[j] + ig * gg;
            rcv[j] = rv; og4[j] = og;
            s2 += rv; q2 += rv * rv;
        }
        #pragma unroll
        for (int off = 1; off < 64; off <<= 1) { s2 += __shfl_xor(s2, off); q2 += __shfl_xor(q2, off); }
        if (lane == 0) { red2[wave] = s2; red2[8 + wave] = q2; }
        bar_lgkm();   // [B] cy partials visible

        float mc, rc;
        {
            const f32x4* r4 = (const f32x4*)red2;
            f32x4 sa = r4[0], sb = r4[1], qa = r4[2], qb = r4[3];
            float s = ((sa[0] + sa[1]) + (sa[2] + sa[3])) + ((sb[0] + sb[1]) + (sb[2] + sb[3]));
            float q = ((qa[0] + qa[1]) + (qa[2] + qa[3])) + ((qb[0] + qb[1]) + (qb[2] + qb[3]));
            mc = s * invH;
            rc = rsqf(q * invH - mc * mc + 1e-5f);
        }

        f16x4 hh;
        #pragma unroll
        for (int j = 0; j < 4; ++j) {
            float lc = (rcv[j] - mc) * rc * ((const float*)&gm4)[j] + ((const float*)&bt4)[j];
            cprev[j] = lc;
            float th = tanhfast(lc);
            float hv = og4[j] * th;
            ((float*)&prevy)[j] = hv;
            ((float*)&prevc)[j] = lc;
            hh[j] = (_Float16)hv;
        }
        *(f16x4*)&hlds[(t >> 5) * PAD_CH + (p & 127)] = hh;
        bar_lgkm();   // [C] hlds ready for next GEMV
    }

    // epilogue: final y row + hy + cy from saved registers
    if (owner) {
        *(float4*)&yout[(size_t)(SEQ - 1) * HD + p] = prevy;
        *(float4*)&hyout[p] = prevy;
        *(float4*)&cyout[p] = prevc;
    }
}

extern "C" void kernel_launch(void* const* d_in, const int* in_sizes, int n_in,
                              void* d_out, int out_size, void* d_ws, size_t ws_size,
                              hipStream_t stream) {
    const float* x   = (const float*)d_in[0];
    const float* wih = (const float*)d_in[1];
    const float* whh = (const float*)d_in[2];
    const float* bih = (const float*)d_in[3];
    const float* bhh = (const float*)d_in[4];
    const float* gam = (const float*)d_in[5];
    const float* bet = (const float*)d_in[6];
    float* out = (float*)d_out;

    char* ws = (char*)d_ws;
    size_t off = 0;
    auto carve = [&](size_t bytes) -> void* {
        void* pp = ws + off;
        off += (bytes + 255) & ~(size_t)255;
        return pp;
    };
    float* xg      = (float*)carve(sizeof(float) * (size_t)SEQ * NG);      // 64 MB
    _Float16* whhf = (_Float16*)carve(sizeof(_Float16) * (size_t)NG * HD); // 32 MB
    float* gates   = (float*)carve(sizeof(float) * 2 * NG);
    float* parts   = (float*)carve(sizeof(float) * 2 * NB * 8 * 2);
    unsigned* barctl = (unsigned*)carve(sizeof(unsigned) * 128 * 64);

    cvt_f16_kernel<<<2048, 256, 0, stream>>>(whh, whhf, NG * HD);
    dim3 ggrid(16, 64);
    gemm_xg<<<ggrid, 256, 0, stream>>>(x, wih, bih, bhh, xg);
    hipMemsetAsync(barctl, 0, sizeof(unsigned) * 128 * 64, stream);

    void* args[] = { (void*)&xg, (void*)&whhf, (void*)&gam, (void*)&bet,
                     (void*)&gates, (void*)&parts, (void*)&barctl, (void*)&out };
    hipLaunchCooperativeKernel((void*)lstm_rec, dim3(NB), dim3(NT), args, 0, stream);
}

// Round 14
// 10029.502 us; speedup vs baseline: 1.2711x; 1.2711x over previous
//
#include <hip/hip_runtime.h>

typedef float f32x2 __attribute__((ext_vector_type(2)));
typedef float f32x4 __attribute__((ext_vector_type(4)));
typedef short bf16x8 __attribute__((ext_vector_type(8)));
typedef _Float16 f16x2 __attribute__((ext_vector_type(2)));
typedef _Float16 f16x4 __attribute__((ext_vector_type(4)));
typedef _Float16 f16x8 __attribute__((ext_vector_type(8)));

#define SEQ 2048
#define HD 2048
#define NG 8192
#define KD 2048
#define NB 256
#define NT 512
#define PAD_CH 136                    // fp16 per 128-elem h-chunk incl. 8 pad (272B stride)

__device__ __forceinline__ unsigned short f32_to_bf16_rne(float f) {
    unsigned int u = __float_as_uint(f);
    u += 0x7FFFu + ((u >> 16) & 1u);
    return (unsigned short)(u >> 16);
}

__global__ void cvt_f16_kernel(const float* __restrict__ in, _Float16* __restrict__ out, int n) {
    for (int i = blockIdx.x * blockDim.x + threadIdx.x; i < n; i += gridDim.x * blockDim.x)
        out[i] = (_Float16)in[i];
}

// ---------------- GEMM: xg[s][g] = sum_k x[s][k] * w_ih[g][k] + b_ih[g] + b_hh[g] ----------------
__global__ __launch_bounds__(256) void gemm_xg(
    const float* __restrict__ A,    // x   [2048][2048]
    const float* __restrict__ B,    // w_ih[8192][2048]
    const float* __restrict__ bih, const float* __restrict__ bhh,
    float* __restrict__ C)          // xg  [2048][8192]
{
    __shared__ unsigned short As[128 * 32];
    __shared__ unsigned short Bs[128 * 32];
    const int tid = threadIdx.x;
    const int bm = blockIdx.x, bn = blockIdx.y;
    const int wave = tid >> 6, lane = tid & 63;
    const int wr = wave >> 1, wc = wave & 1;
    const int l15 = lane & 15, l4 = lane >> 4;

    f32x4 acc[4][4];
    #pragma unroll
    for (int i = 0; i < 4; ++i)
        #pragma unroll
        for (int j = 0; j < 4; ++j) {
            f32x4 z = {0.f, 0.f, 0.f, 0.f};
            acc[i][j] = z;
        }

    for (int k0 = 0; k0 < KD; k0 += 32) {
        #pragma unroll
        for (int i = 0; i < 2; ++i) {
            int idx = tid + i * 256;
            int row = idx >> 2, c8 = idx & 3;
            const float* ga = A + (size_t)(bm * 128 + row) * KD + k0 + c8 * 8;
            float4 a0 = *(const float4*)ga;
            float4 a1 = *(const float4*)(ga + 4);
            bf16x8 av;
            av[0] = (short)f32_to_bf16_rne(a0.x); av[1] = (short)f32_to_bf16_rne(a0.y);
            av[2] = (short)f32_to_bf16_rne(a0.z); av[3] = (short)f32_to_bf16_rne(a0.w);
            av[4] = (short)f32_to_bf16_rne(a1.x); av[5] = (short)f32_to_bf16_rne(a1.y);
            av[6] = (short)f32_to_bf16_rne(a1.z); av[7] = (short)f32_to_bf16_rne(a1.w);
            *(bf16x8*)&As[row * 32 + c8 * 8] = av;
            const float* gb = B + (size_t)(bn * 128 + row) * KD + k0 + c8 * 8;
            float4 b0 = *(const float4*)gb;
            float4 b1 = *(const float4*)(gb + 4);
            bf16x8 bv;
            bv[0] = (short)f32_to_bf16_rne(b0.x); bv[1] = (short)f32_to_bf16_rne(b0.y);
            bv[2] = (short)f32_to_bf16_rne(b0.z); bv[3] = (short)f32_to_bf16_rne(b0.w);
            bv[4] = (short)f32_to_bf16_rne(b1.x); bv[5] = (short)f32_to_bf16_rne(b1.y);
            bv[6] = (short)f32_to_bf16_rne(b1.z); bv[7] = (short)f32_to_bf16_rne(b1.w);
            *(bf16x8*)&Bs[row * 32 + c8 * 8] = bv;
        }
        __syncthreads();
        bf16x8 af[4], bfr[4];
        #pragma unroll
        for (int m = 0; m < 4; ++m) af[m] = *(const bf16x8*)&As[(wr * 64 + m * 16 + l15) * 32 + l4 * 8];
        #pragma unroll
        for (int n = 0; n < 4; ++n) bfr[n] = *(const bf16x8*)&Bs[(wc * 64 + n * 16 + l15) * 32 + l4 * 8];
        #pragma unroll
        for (int m = 0; m < 4; ++m)
            #pragma unroll
            for (int n = 0; n < 4; ++n)
                acc[m][n] = __builtin_amdgcn_mfma_f32_16x16x32_bf16(af[m], bfr[n], acc[m][n], 0, 0, 0);
        __syncthreads();
    }
    #pragma unroll
    for (int m = 0; m < 4; ++m) {
        #pragma unroll
        for (int n = 0; n < 4; ++n) {
            int col = bn * 128 + wc * 64 + n * 16 + l15;
            float bias = bih[col] + bhh[col];
            int row0 = bm * 128 + wr * 64 + m * 16 + l4 * 4;
            #pragma unroll
            for (int r = 0; r < 4; ++r)
                C[(size_t)(row0 + r) * NG + col] = acc[m][n][r] + bias;
        }
    }
}

// ---- LLC-coherent primitives (agent scope; no cache-wide fences anywhere) ----
__device__ __forceinline__ void st_llc16(float* p, f32x4 v) {
    asm volatile("global_store_dwordx4 %0, %1, off sc0 sc1" :: "v"(p), "v"(v) : "memory");
}
__device__ __forceinline__ void st_llc8(float* p, f32x2 v) {
    asm volatile("global_store_dwordx2 %0, %1, off sc0 sc1" :: "v"(p), "v"(v) : "memory");
}
// issue 4 coherent 16B partial loads at p+0/16/32/48, NO wait
__device__ __forceinline__ void ld_llc_issue_p(const float* p, f32x4& a, f32x4& b, f32x4& c, f32x4& d) {
    asm volatile(
        "global_load_dwordx4 %0, %4, off sc0 sc1\n\t"
        "global_load_dwordx4 %1, %4, off offset:16 sc0 sc1\n\t"
        "global_load_dwordx4 %2, %4, off offset:32 sc0 sc1\n\t"
        "global_load_dwordx4 %3, %4, off offset:48 sc0 sc1"
        : "=&v"(a), "=&v"(b), "=&v"(c), "=&v"(d)
        : "v"(p)
        : "memory");
}
// issue 4 coherent 16B gate loads, NO wait
__device__ __forceinline__ void ld_llc_issue4(const float* p0, const float* p1,
                                              const float* p2, const float* p3,
                                              f32x4& a, f32x4& b, f32x4& c, f32x4& d) {
    asm volatile(
        "global_load_dwordx4 %0, %4, off sc0 sc1\n\t"
        "global_load_dwordx4 %1, %5, off sc0 sc1\n\t"
        "global_load_dwordx4 %2, %6, off sc0 sc1\n\t"
        "global_load_dwordx4 %3, %7, off sc0 sc1"
        : "=&v"(a), "=&v"(b), "=&v"(c), "=&v"(d)
        : "v"(p0), "v"(p1), "v"(p2), "v"(p3)
        : "memory");
}
// untracked plain 16B load (xg prefetch; normal caching, issued LAST)
__device__ __forceinline__ void ld_gl16(const float* p, f32x4& a) {
    asm volatile("global_load_dwordx4 %0, %1, off" : "=&v"(a) : "v"(p) : "memory");
}
// counted waits (issue order per wave: [y?] [partials x4?] gq x4, xg) — xg ALWAYS newest
__device__ __forceinline__ void wait_vm5(f32x4& a, f32x4& b, f32x4& c, f32x4& d) {
    asm volatile("s_waitcnt vmcnt(5)" : "+v"(a), "+v"(b), "+v"(c), "+v"(d) :: "memory");
    __builtin_amdgcn_sched_barrier(0);
}
__device__ __forceinline__ void wait_vm1(f32x4& a, f32x4& b, f32x4& c, f32x4& d) {
    asm volatile("s_waitcnt vmcnt(1)" : "+v"(a), "+v"(b), "+v"(c), "+v"(d) :: "memory");
    __builtin_amdgcn_sched_barrier(0);
}
__device__ __forceinline__ void wait_vm0_1(f32x4& a) {
    asm volatile("s_waitcnt vmcnt(0)" : "+v"(a) :: "memory");
    __builtin_amdgcn_sched_barrier(0);
}

__device__ __forceinline__ float rcpf(float x) { return __builtin_amdgcn_rcpf(x); }
__device__ __forceinline__ float rsqf(float x) { return __builtin_amdgcn_rsqf(x); }
__device__ __forceinline__ float sigf(float x) { return rcpf(1.0f + __expf(-x)); }
__device__ __forceinline__ float tanhfast(float x) {
    float ax = fabsf(x);
    float e = __expf(-2.0f * ax);
    return __builtin_copysignf((1.0f - e) * rcpf(1.0f + e), x);
}

// intra-block barrier draining ONLY LDS (lgkm) — leaves global loads in flight
__device__ __forceinline__ void bar_lgkm() {
    asm volatile("s_waitcnt lgkmcnt(0)" ::: "memory");
    __builtin_amdgcn_s_barrier();
}
// full-drain barrier (pre-arrival: gate+partial stores must be at LLC)
__device__ __forceinline__ void bar_full() {
    asm volatile("s_waitcnt vmcnt(0) lgkmcnt(0)" ::: "memory");
    __builtin_amdgcn_s_barrier();
}

// barctl layout (unsigned, 64-word = 256B spacing):
//   [g*64]     g=0..7  group arrival counters (32 blocks each; RMW only)
//   [(8+g)*64] g=0..7  grpdone lines (write-once per step; poll targets)
// Poll targets DISJOINT from RMW targets, block-level arrival only — load-bearing:
// R8 (poll-the-counters) and R13 (per-wave arrival) both regressed 30-90% from
// barrier-fabric congestion.
#define DONE_OFF (8 * 64)

// ---------------- Persistent recurrence: R11 barrier + deferred y-store ----------------
__global__ __launch_bounds__(512, 2) void lstm_rec(
    const float* __restrict__ xg,          // [SEQ][NG]
    const _Float16* __restrict__ Whh,      // [NG][HD] fp16
    const float* __restrict__ gamma,       // [5][HD]
    const float* __restrict__ beta,        // [5][HD]
    float* __restrict__ gates,             // [2][NG] f32, double-buffered
    float* __restrict__ partials,          // [2][NB*8*2] f32 {s,q} per (block,wave), dbuffered
    unsigned* __restrict__ barctl,
    float* __restrict__ yout)              // y[SEQ][HD], hy[HD], cy[HD]
{
    __shared__ _Float16 hlds[16 * PAD_CH];
    __shared__ __align__(16) float red2[16];    // cy partials [s: w | q: 8+w]
    __shared__ __align__(16) float statsmem[8]; // 4 gates x {m, r}

    const int b = blockIdx.x;
    const int t = threadIdx.x;
    const int wave = t >> 6, lane = t & 63;
    const int p = t * 4;                   // this thread's 4 H-positions

    unsigned* grpcnt = barctl + (b >> 5) * 64;

    const int row = t >> 4, sub = t & 15;  // GEMV: row 0..31, 128-col chunk
    const int grow = b * 32 + row;
    const bool owner = ((t >> 1) == b);    // threads 2b,2b+1 own y-slice [8b,8b+8)

    // ---- W strip -> 64 VGPRs (one-time) ----
    f16x8 wreg[16];
    {
        const _Float16* wsrc = Whh + (size_t)grow * HD + sub * 128;
        #pragma unroll
        for (int i = 0; i < 16; ++i) wreg[i] = *(const f16x8*)(wsrc + i * 8);
    }
    for (int k = t; k < 16 * PAD_CH; k += NT) hlds[k] = (_Float16)0.0f;

    float4 gm[4], bt[4];
    #pragma unroll
    for (int g = 0; g < 4; ++g) {
        gm[g] = *(const float4*)&gamma[g * HD + p];
        bt[g] = *(const float4*)&beta[g * HD + p];
    }
    float4 gm4 = *(const float4*)&gamma[4 * HD + p];
    float4 bt4 = *(const float4*)&beta[4 * HD + p];

    float* hyout = yout + (size_t)SEQ * HD;
    float* cyout = hyout + HD;
    const float invH = 1.0f / 2048.0f;

    float cprev[4] = {0.f, 0.f, 0.f, 0.f};
    float4 prevy = {0.f, 0.f, 0.f, 0.f};  // previous step's h slice (owner writes post-release)
    float4 prevc = {0.f, 0.f, 0.f, 0.f};

    // lane0 of wave w holds xg f32x4 for rows b*32 + 4w .. +3
    f32x4 xg4 = {0.f, 0.f, 0.f, 0.f};
    if (lane == 0) xg4 = *(const f32x4*)(xg + b * 32 + wave * 4);

    const _Float16* hch = hlds + sub * PAD_CH;
    __syncthreads();

    for (int step = 0; step < SEQ; ++step) {
        float* gb = gates + (size_t)(step & 1) * NG;
        float* pb = partials + (size_t)(step & 1) * (NB * 8 * 2);
        const unsigned gen = (unsigned)(step + 1);

        // retire xg prefetch before use
        wait_vm0_1(xg4);

        // ---------- GEMV from registers; h via LDS broadcast ----------
        float accv[4] = {0.f, 0.f, 0.f, 0.f};
        #pragma unroll
        for (int i = 0; i < 16; ++i) {
            f16x8 hv = *(const f16x8*)(hch + i * 8);
            const f16x2* w2 = (const f16x2*)&wreg[i];
            const f16x2* h2 = (const f16x2*)&hv;
            float x = accv[i & 3];
            x = __builtin_amdgcn_fdot2(w2[0], h2[0], x, false);
            x = __builtin_amdgcn_fdot2(w2[1], h2[1], x, false);
            x = __builtin_amdgcn_fdot2(w2[2], h2[2], x, false);
            x = __builtin_amdgcn_fdot2(w2[3], h2[3], x, false);
            accv[i & 3] = x;
        }
        float r = (accv[0] + accv[1]) + (accv[2] + accv[3]);
        #pragma unroll
        for (int off = 1; off < 16; off <<= 1) r += __shfl_xor(r, off);
        float r1 = __shfl(r, 16), r2 = __shfl(r, 32), r3 = __shfl(r, 48);
        if (lane == 0) {
            float g0 = r + xg4[0], g1 = r1 + xg4[1], g2 = r2 + xg4[2], g3 = r3 + xg4[3];
            f32x4 gv4 = {g0, g1, g2, g3};
            st_llc16(&gb[b * 32 + wave * 4], gv4);
            f32x2 pq = {(g0 + g1) + (g2 + g3),
                        (g0 * g0 + g1 * g1) + (g2 * g2 + g3 * g3)};
            st_llc8(&pb[(b * 8 + wave) * 2], pq);
        }

        bar_full();   // drains gate+partial stores (vmcnt 0) before arrival

        // ---------- arrival: block-level grp add; completer writes grpdone ----------
        if (t == 0) {
            asm volatile("" ::: "memory");
            unsigned o1 = __hip_atomic_fetch_add(grpcnt, 1u, __ATOMIC_RELAXED, __HIP_MEMORY_SCOPE_AGENT);
            if (o1 == gen * 32u - 1u)
                __hip_atomic_store(barctl + DONE_OFF + (b >> 5) * 64, gen,
                                   __ATOMIC_RELAXED, __HIP_MEMORY_SCOPE_AGENT);
        }
        // ---------- release: every wave polls the 8 write-once grpdone lines ----------
        for (;;) {
            unsigned v = 0xFFFFFFFFu;
            if (lane < 8)
                v = __hip_atomic_load(barctl + DONE_OFF + lane * 64, __ATOMIC_RELAXED, __HIP_MEMORY_SCOPE_AGENT);
            if (__all(v >= gen)) break;
            __builtin_amdgcn_s_sleep(1);
        }
        asm volatile("" ::: "memory");

        // ---------- post-release: y-store (prev step), then counted-vmcnt loads ----------
        if (step > 0 && owner)
            *(float4*)&yout[(size_t)(step - 1) * HD + p] = prevy;

        f32x4 pa, pbv, pc, pd;
        if (wave < 4)
            ld_llc_issue_p(&pb[wave * 1024 + lane * 16], pa, pbv, pc, pd);
        f32x4 gq[4];
        ld_llc_issue4(&gb[0 * HD + p], &gb[1 * HD + p], &gb[2 * HD + p], &gb[3 * HD + p],
                      gq[0], gq[1], gq[2], gq[3]);
        if (lane == 0)   // unconditional (modular) -> vmcnt counts identical every step
            ld_gl16(xg + (size_t)((step + 1) & (SEQ - 1)) * NG + b * 32 + wave * 4, xg4);

        // waves 0-3: stats from partials; waits only through the partials (vmcnt(5))
        if (wave < 4) {
            wait_vm5(pa, pbv, pc, pd);
            float s = ((pa[0] + pa[2]) + (pbv[0] + pbv[2])) + ((pc[0] + pc[2]) + (pd[0] + pd[2]));
            float q = ((pa[1] + pa[3]) + (pbv[1] + pbv[3])) + ((pc[1] + pc[3]) + (pd[1] + pd[3]));
            #pragma unroll
            for (int off = 1; off < 64; off <<= 1) { s += __shfl_xor(s, off); q += __shfl_xor(q, off); }
            if (lane == 0) {
                float m = s * invH;
                statsmem[wave * 2] = m;
                statsmem[wave * 2 + 1] = rsqf(q * invH - m * m + 1e-5f);
            }
        }
        bar_lgkm();   // [A] stats visible (lgkm only: gq+xg stay in flight)

        wait_vm1(gq[0], gq[1], gq[2], gq[3]);   // gq ready; xg remains in flight
        float mg[4], rg[4];
        {
            const f32x4* sm = (const f32x4*)statsmem;
            f32x4 s0 = sm[0], s1 = sm[1];
            mg[0] = s0[0]; rg[0] = s0[1]; mg[1] = s0[2]; rg[1] = s0[3];
            mg[2] = s1[0]; rg[2] = s1[1]; mg[3] = s1[2]; rg[3] = s1[3];
        }

        float rcv[4], og4[4];
        float s2 = 0.f, q2 = 0.f;
        #pragma unroll
        for (int j = 0; j < 4; ++j) {
            float li = (gq[0][j] - mg[0]) * rg[0] * ((const float*)&gm[0])[j] + ((const float*)&bt[0])[j];
            float lf = (gq[1][j] - mg[1]) * rg[1] * ((const float*)&gm[1])[j] + ((const float*)&bt[1])[j];
            float lg = (gq[2][j] - mg[2]) * rg[2] * ((const float*)&gm[2])[j] + ((const float*)&bt[2])[j];
            float lo = (gq[3][j] - mg[3]) * rg[3] * ((const float*)&gm[3])[j] + ((const float*)&bt[3])[j];
            float ig = sigf(li);
            float fg = sigf(lf);
            float gg = tanhfast(lg);
            float og = sigf(lo);
            float rv = fg * cprev[j] + ig * gg;
            rcv[j] = rv; og4[j] = og;
            s2 += rv; q2 += rv * rv;
        }
        #pragma unroll
        for (int off = 1; off < 64; off <<= 1) { s2 += __shfl_xor(s2, off); q2 += __shfl_xor(q2, off); }
        if (lane == 0) { red2[wave] = s2; red2[8 + wave] = q2; }
        bar_lgkm();   // [B] cy partials visible

        float mc, rc;
        {
            const f32x4* r4 = (const f32x4*)red2;
            f32x4 sa = r4[0], sb = r4[1], qa = r4[2], qb = r4[3];
            float s = ((sa[0] + sa[1]) + (sa[2] + sa[3])) + ((sb[0] + sb[1]) + (sb[2] + sb[3]));
            float q = ((qa[0] + qa[1]) + (qa[2] + qa[3])) + ((qb[0] + qb[1]) + (qb[2] + qb[3]));
            mc = s * invH;
            rc = rsqf(q * invH - mc * mc + 1e-5f);
        }

        f16x4 hh;
        #pragma unroll
        for (int j = 0; j < 4; ++j) {
            float lc = (rcv[j] - mc) * rc * ((const float*)&gm4)[j] + ((const float*)&bt4)[j];
            cprev[j] = lc;
            float th = tanhfast(lc);
            float hv = og4[j] * th;
            ((float*)&prevy)[j] = hv;
            ((float*)&prevc)[j] = lc;
            hh[j] = (_Float16)hv;
        }
        *(f16x4*)&hlds[(t >> 5) * PAD_CH + (p & 127)] = hh;
        bar_lgkm();   // [C] hlds ready for next GEMV
    }

    // epilogue: final y row + hy + cy from saved registers
    if (owner) {
        *(float4*)&yout[(size_t)(SEQ - 1) * HD + p] = prevy;
        *(float4*)&hyout[p] = prevy;
        *(float4*)&cyout[p] = prevc;
    }
}

extern "C" void kernel_launch(void* const* d_in, const int* in_sizes, int n_in,
                              void* d_out, int out_size, void* d_ws, size_t ws_size,
                              hipStream_t stream) {
    const float* x   = (const float*)d_in[0];
    const float* wih = (const float*)d_in[1];
    const float* whh = (const float*)d_in[2];
    const float* bih = (const float*)d_in[3];
    const float* bhh = (const float*)d_in[4];
    const float* gam = (const float*)d_in[5];
    const float* bet = (const float*)d_in[6];
    float* out = (float*)d_out;

    char* ws = (char*)d_ws;
    size_t off = 0;
    auto carve = [&](size_t bytes) -> void* {
        void* pp = ws + off;
        off += (bytes + 255) & ~(size_t)255;
        return pp;
    };
    float* xg      = (float*)carve(sizeof(float) * (size_t)SEQ * NG);      // 64 MB
    _Float16* whhf = (_Float16*)carve(sizeof(_Float16) * (size_t)NG * HD); // 32 MB
    float* gates   = (float*)carve(sizeof(float) * 2 * NG);
    float* parts   = (float*)carve(sizeof(float) * 2 * NB * 8 * 2);
    unsigned* barctl = (unsigned*)carve(sizeof(unsigned) * 16 * 64);

    cvt_f16_kernel<<<2048, 256, 0, stream>>>(whh, whhf, NG * HD);
    dim3 ggrid(16, 64);
    gemm_xg<<<ggrid, 256, 0, stream>>>(x, wih, bih, bhh, xg);
    hipMemsetAsync(barctl, 0, sizeof(unsigned) * 16 * 64, stream);

    void* args[] = { (void*)&xg, (void*)&whhf, (void*)&gam, (void*)&bet,
                     (void*)&gates, (void*)&parts, (void*)&barctl, (void*)&out };
    hipLaunchCooperativeKernel((void*)lstm_rec, dim3(NB), dim3(NT), args, 0, stream);
}

// Round 15
// 9896.093 us; speedup vs baseline: 1.2883x; 1.0135x over previous
//
#include <hip/hip_runtime.h>

typedef float f32x2 __attribute__((ext_vector_type(2)));
typedef float f32x4 __attribute__((ext_vector_type(4)));
typedef short bf16x8 __attribute__((ext_vector_type(8)));
typedef _Float16 f16x2 __attribute__((ext_vector_type(2)));
typedef _Float16 f16x4 __attribute__((ext_vector_type(4)));
typedef _Float16 f16x8 __attribute__((ext_vector_type(8)));

#define SEQ 2048
#define HD 2048
#define NG 8192
#define KD 2048
#define NB 256
#define NT 512
#define PAD_CH 136                    // fp16 per 128-elem h-chunk incl. 8 pad (272B stride)

__device__ __forceinline__ unsigned short f32_to_bf16_rne(float f) {
    unsigned int u = __float_as_uint(f);
    u += 0x7FFFu + ((u >> 16) & 1u);
    return (unsigned short)(u >> 16);
}

__global__ void cvt_f16_kernel(const float* __restrict__ in, _Float16* __restrict__ out, int n) {
    for (int i = blockIdx.x * blockDim.x + threadIdx.x; i < n; i += gridDim.x * blockDim.x)
        out[i] = (_Float16)in[i];
}

// ---------------- GEMM: xg[s][g] = sum_k x[s][k] * w_ih[g][k] + b_ih[g] + b_hh[g] ----------------
__global__ __launch_bounds__(256) void gemm_xg(
    const float* __restrict__ A,    // x   [2048][2048]
    const float* __restrict__ B,    // w_ih[8192][2048]
    const float* __restrict__ bih, const float* __restrict__ bhh,
    float* __restrict__ C)          // xg  [2048][8192]
{
    __shared__ unsigned short As[128 * 32];
    __shared__ unsigned short Bs[128 * 32];
    const int tid = threadIdx.x;
    const int bm = blockIdx.x, bn = blockIdx.y;
    const int wave = tid >> 6, lane = tid & 63;
    const int wr = wave >> 1, wc = wave & 1;
    const int l15 = lane & 15, l4 = lane >> 4;

    f32x4 acc[4][4];
    #pragma unroll
    for (int i = 0; i < 4; ++i)
        #pragma unroll
        for (int j = 0; j < 4; ++j) {
            f32x4 z = {0.f, 0.f, 0.f, 0.f};
            acc[i][j] = z;
        }

    for (int k0 = 0; k0 < KD; k0 += 32) {
        #pragma unroll
        for (int i = 0; i < 2; ++i) {
            int idx = tid + i * 256;
            int row = idx >> 2, c8 = idx & 3;
            const float* ga = A + (size_t)(bm * 128 + row) * KD + k0 + c8 * 8;
            float4 a0 = *(const float4*)ga;
            float4 a1 = *(const float4*)(ga + 4);
            bf16x8 av;
            av[0] = (short)f32_to_bf16_rne(a0.x); av[1] = (short)f32_to_bf16_rne(a0.y);
            av[2] = (short)f32_to_bf16_rne(a0.z); av[3] = (short)f32_to_bf16_rne(a0.w);
            av[4] = (short)f32_to_bf16_rne(a1.x); av[5] = (short)f32_to_bf16_rne(a1.y);
            av[6] = (short)f32_to_bf16_rne(a1.z); av[7] = (short)f32_to_bf16_rne(a1.w);
            *(bf16x8*)&As[row * 32 + c8 * 8] = av;
            const float* gb = B + (size_t)(bn * 128 + row) * KD + k0 + c8 * 8;
            float4 b0 = *(const float4*)gb;
            float4 b1 = *(const float4*)(gb + 4);
            bf16x8 bv;
            bv[0] = (short)f32_to_bf16_rne(b0.x); bv[1] = (short)f32_to_bf16_rne(b0.y);
            bv[2] = (short)f32_to_bf16_rne(b0.z); bv[3] = (short)f32_to_bf16_rne(b0.w);
            bv[4] = (short)f32_to_bf16_rne(b1.x); bv[5] = (short)f32_to_bf16_rne(b1.y);
            bv[6] = (short)f32_to_bf16_rne(b1.z); bv[7] = (short)f32_to_bf16_rne(b1.w);
            *(bf16x8*)&Bs[row * 32 + c8 * 8] = bv;
        }
        __syncthreads();
        bf16x8 af[4], bfr[4];
        #pragma unroll
        for (int m = 0; m < 4; ++m) af[m] = *(const bf16x8*)&As[(wr * 64 + m * 16 + l15) * 32 + l4 * 8];
        #pragma unroll
        for (int n = 0; n < 4; ++n) bfr[n] = *(const bf16x8*)&Bs[(wc * 64 + n * 16 + l15) * 32 + l4 * 8];
        #pragma unroll
        for (int m = 0; m < 4; ++m)
            #pragma unroll
            for (int n = 0; n < 4; ++n)
                acc[m][n] = __builtin_amdgcn_mfma_f32_16x16x32_bf16(af[m], bfr[n], acc[m][n], 0, 0, 0);
        __syncthreads();
    }
    #pragma unroll
    for (int m = 0; m < 4; ++m) {
        #pragma unroll
        for (int n = 0; n < 4; ++n) {
            int col = bn * 128 + wc * 64 + n * 16 + l15;
            float bias = bih[col] + bhh[col];
            int row0 = bm * 128 + wr * 64 + m * 16 + l4 * 4;
            #pragma unroll
            for (int r = 0; r < 4; ++r)
                C[(size_t)(row0 + r) * NG + col] = acc[m][n][r] + bias;
        }
    }
}

// ---- LLC-coherent primitives (agent scope; no cache-wide fences anywhere) ----
__device__ __forceinline__ void st_llc16(float* p, f32x4 v) {
    asm volatile("global_store_dwordx4 %0, %1, off sc0 sc1" :: "v"(p), "v"(v) : "memory");
}
__device__ __forceinline__ void st_llc8(float* p, f32x2 v) {
    asm volatile("global_store_dwordx2 %0, %1, off sc0 sc1" :: "v"(p), "v"(v) : "memory");
}
// issue 4 coherent 16B partial loads at p+0/16/32/48, NO wait
__device__ __forceinline__ void ld_llc_issue_p(const float* p, f32x4& a, f32x4& b, f32x4& c, f32x4& d) {
    asm volatile(
        "global_load_dwordx4 %0, %4, off sc0 sc1\n\t"
        "global_load_dwordx4 %1, %4, off offset:16 sc0 sc1\n\t"
        "global_load_dwordx4 %2, %4, off offset:32 sc0 sc1\n\t"
        "global_load_dwordx4 %3, %4, off offset:48 sc0 sc1"
        : "=&v"(a), "=&v"(b), "=&v"(c), "=&v"(d)
        : "v"(p)
        : "memory");
}
// issue 4 coherent 16B gate loads, NO wait
__device__ __forceinline__ void ld_llc_issue4(const float* p0, const float* p1,
                                              const float* p2, const float* p3,
                                              f32x4& a, f32x4& b, f32x4& c, f32x4& d) {
    asm volatile(
        "global_load_dwordx4 %0, %4, off sc0 sc1\n\t"
        "global_load_dwordx4 %1, %5, off sc0 sc1\n\t"
        "global_load_dwordx4 %2, %6, off sc0 sc1\n\t"
        "global_load_dwordx4 %3, %7, off sc0 sc1"
        : "=&v"(a), "=&v"(b), "=&v"(c), "=&v"(d)
        : "v"(p0), "v"(p1), "v"(p2), "v"(p3)
        : "memory");
}
// untracked plain 16B load (xg prefetch; normal caching, issued LAST)
__device__ __forceinline__ void ld_gl16(const float* p, f32x4& a) {
    asm volatile("global_load_dwordx4 %0, %1, off" : "=&v"(a) : "v"(p) : "memory");
}
// counted waits (issue order per wave: [partials x4?] gq x4, xg, [y at loop end]) — xg newest load
__device__ __forceinline__ void wait_vm5(f32x4& a, f32x4& b, f32x4& c, f32x4& d) {
    asm volatile("s_waitcnt vmcnt(5)" : "+v"(a), "+v"(b), "+v"(c), "+v"(d) :: "memory");
    __builtin_amdgcn_sched_barrier(0);
}
__device__ __forceinline__ void wait_vm1(f32x4& a, f32x4& b, f32x4& c, f32x4& d) {
    asm volatile("s_waitcnt vmcnt(1)" : "+v"(a), "+v"(b), "+v"(c), "+v"(d) :: "memory");
    __builtin_amdgcn_sched_barrier(0);
}
__device__ __forceinline__ void wait_vm0_1(f32x4& a) {
    asm volatile("s_waitcnt vmcnt(0)" : "+v"(a) :: "memory");
    __builtin_amdgcn_sched_barrier(0);
}

__device__ __forceinline__ float rcpf(float x) { return __builtin_amdgcn_rcpf(x); }
__device__ __forceinline__ float rsqf(float x) { return __builtin_amdgcn_rsqf(x); }
__device__ __forceinline__ float sigf(float x) { return rcpf(1.0f + __expf(-x)); }
__device__ __forceinline__ float tanhfast(float x) {
    float ax = fabsf(x);
    float e = __expf(-2.0f * ax);
    return __builtin_copysignf((1.0f - e) * rcpf(1.0f + e), x);
}

// intra-block barrier draining ONLY LDS (lgkm) — leaves global loads in flight
__device__ __forceinline__ void bar_lgkm() {
    asm volatile("s_waitcnt lgkmcnt(0)" ::: "memory");
    __builtin_amdgcn_s_barrier();
}
// full-drain barrier (pre-arrival: gate+partial+y stores must be at LLC)
__device__ __forceinline__ void bar_full() {
    asm volatile("s_waitcnt vmcnt(0) lgkmcnt(0)" ::: "memory");
    __builtin_amdgcn_s_barrier();
}

// barctl layout (unsigned, 64-word = 256B spacing):
//   [g*64]      g=0..15  group arrival counters (16 blocks each; RMW only)
//   [(16+g)*64] g=0..15  grpdone lines (write-once per step; poll targets)
// Poll targets DISJOINT from RMW targets, block-level arrival only — load-bearing:
// R8 (poll-the-counters) and R13 (per-wave arrival) both regressed 30-90% from
// barrier-fabric congestion. 16 groups (vs R11's 8) halves the same-line atomic
// arrival tail; per-line reader count unchanged (2048 waves/line).
#define DONE_OFF (16 * 64)

// ---------------- Persistent recurrence: 16-group two-hop barrier per step ----------------
__global__ __launch_bounds__(512, 2) void lstm_rec(
    const float* __restrict__ xg,          // [SEQ][NG]
    const _Float16* __restrict__ Whh,      // [NG][HD] fp16
    const float* __restrict__ gamma,       // [5][HD]
    const float* __restrict__ beta,        // [5][HD]
    float* __restrict__ gates,             // [2][NG] f32, double-buffered
    float* __restrict__ partials,          // [2][NB*8*2] f32 {s,q} per (block,wave), dbuffered
    unsigned* __restrict__ barctl,
    float* __restrict__ yout)              // y[SEQ][HD], hy[HD], cy[HD]
{
    __shared__ _Float16 hlds[16 * PAD_CH];
    __shared__ __align__(16) float red2[16];    // cy partials [s: w | q: 8+w]
    __shared__ __align__(16) float statsmem[8]; // 4 gates x {m, r}

    const int b = blockIdx.x;
    const int t = threadIdx.x;
    const int wave = t >> 6, lane = t & 63;
    const int p = t * 4;                   // this thread's 4 H-positions

    unsigned* grpcnt = barctl + (b >> 4) * 64;

    const int row = t >> 4, sub = t & 15;  // GEMV: row 0..31, 128-col chunk
    const int grow = b * 32 + row;
    const bool owner = ((t >> 1) == b);    // threads 2b,2b+1 own y-slice [8b,8b+8)

    // ---- W strip -> 64 VGPRs (one-time) ----
    f16x8 wreg[16];
    {
        const _Float16* wsrc = Whh + (size_t)grow * HD + sub * 128;
        #pragma unroll
        for (int i = 0; i < 16; ++i) wreg[i] = *(const f16x8*)(wsrc + i * 8);
    }
    for (int k = t; k < 16 * PAD_CH; k += NT) hlds[k] = (_Float16)0.0f;

    float4 gm[4], bt[4];
    #pragma unroll
    for (int g = 0; g < 4; ++g) {
        gm[g] = *(const float4*)&gamma[g * HD + p];
        bt[g] = *(const float4*)&beta[g * HD + p];
    }
    float4 gm4 = *(const float4*)&gamma[4 * HD + p];
    float4 bt4 = *(const float4*)&beta[4 * HD + p];

    float* hyout = yout + (size_t)SEQ * HD;
    float* cyout = hyout + HD;
    const float invH = 1.0f / 2048.0f;

    float cprev[4] = {0.f, 0.f, 0.f, 0.f};

    // lane0 of wave w holds xg f32x4 for rows b*32 + 4w .. +3
    f32x4 xg4 = {0.f, 0.f, 0.f, 0.f};
    if (lane == 0) xg4 = *(const f32x4*)(xg + b * 32 + wave * 4);

    const _Float16* hch = hlds + sub * PAD_CH;
    __syncthreads();

    for (int step = 0; step < SEQ; ++step) {
        float* gb = gates + (size_t)(step & 1) * NG;
        float* pb = partials + (size_t)(step & 1) * (NB * 8 * 2);
        const unsigned gen = (unsigned)(step + 1);

        // retire xg prefetch (+ prior y-store ack) before use
        wait_vm0_1(xg4);

        // ---------- GEMV from registers; h via LDS broadcast ----------
        float accv[4] = {0.f, 0.f, 0.f, 0.f};
        #pragma unroll
        for (int i = 0; i < 16; ++i) {
            f16x8 hv = *(const f16x8*)(hch + i * 8);
            const f16x2* w2 = (const f16x2*)&wreg[i];
            const f16x2* h2 = (const f16x2*)&hv;
            float x = accv[i & 3];
            x = __builtin_amdgcn_fdot2(w2[0], h2[0], x, false);
            x = __builtin_amdgcn_fdot2(w2[1], h2[1], x, false);
            x = __builtin_amdgcn_fdot2(w2[2], h2[2], x, false);
            x = __builtin_amdgcn_fdot2(w2[3], h2[3], x, false);
            accv[i & 3] = x;
        }
        float r = (accv[0] + accv[1]) + (accv[2] + accv[3]);
        #pragma unroll
        for (int off = 1; off < 16; off <<= 1) r += __shfl_xor(r, off);
        float r1 = __shfl(r, 16), r2 = __shfl(r, 32), r3 = __shfl(r, 48);
        if (lane == 0) {
            float g0 = r + xg4[0], g1 = r1 + xg4[1], g2 = r2 + xg4[2], g3 = r3 + xg4[3];
            f32x4 gv4 = {g0, g1, g2, g3};
            st_llc16(&gb[b * 32 + wave * 4], gv4);
            f32x2 pq = {(g0 + g1) + (g2 + g3),
                        (g0 * g0 + g1 * g1) + (g2 * g2 + g3 * g3)};
            st_llc8(&pb[(b * 8 + wave) * 2], pq);
        }

        bar_full();   // drains gate+partial (+y) stores (vmcnt 0) before arrival

        // ---------- arrival: block-level grp add; completer writes grpdone ----------
        if (t == 0) {
            asm volatile("" ::: "memory");
            unsigned o1 = __hip_atomic_fetch_add(grpcnt, 1u, __ATOMIC_RELAXED, __HIP_MEMORY_SCOPE_AGENT);
            if (o1 == gen * 16u - 1u)
                __hip_atomic_store(barctl + DONE_OFF + (b >> 4) * 64, gen,
                                   __ATOMIC_RELAXED, __HIP_MEMORY_SCOPE_AGENT);
        }
        // ---------- release: every wave polls the 16 write-once grpdone lines ----------
        for (;;) {
            unsigned v = 0xFFFFFFFFu;
            if (lane < 16)
                v = __hip_atomic_load(barctl + DONE_OFF + lane * 64, __ATOMIC_RELAXED, __HIP_MEMORY_SCOPE_AGENT);
            if (__all(v >= gen)) break;
            __builtin_amdgcn_s_sleep(1);
        }
        asm volatile("" ::: "memory");

        // ---------- post-phase: counted-vmcnt overlapped loads ----------
        f32x4 pa, pbv, pc, pd;
        if (wave < 4)
            ld_llc_issue_p(&pb[wave * 1024 + lane * 16], pa, pbv, pc, pd);
        f32x4 gq[4];
        ld_llc_issue4(&gb[0 * HD + p], &gb[1 * HD + p], &gb[2 * HD + p], &gb[3 * HD + p],
                      gq[0], gq[1], gq[2], gq[3]);
        if (lane == 0)   // unconditional (modular) -> vmcnt counts identical every step
            ld_gl16(xg + (size_t)((step + 1) & (SEQ - 1)) * NG + b * 32 + wave * 4, xg4);

        // waves 0-3: stats from partials; waits only through the partials (vmcnt(5))
        if (wave < 4) {
            wait_vm5(pa, pbv, pc, pd);
            float s = ((pa[0] + pa[2]) + (pbv[0] + pbv[2])) + ((pc[0] + pc[2]) + (pd[0] + pd[2]));
            float q = ((pa[1] + pa[3]) + (pbv[1] + pbv[3])) + ((pc[1] + pc[3]) + (pd[1] + pd[3]));
            #pragma unroll
            for (int off = 1; off < 64; off <<= 1) { s += __shfl_xor(s, off); q += __shfl_xor(q, off); }
            if (lane == 0) {
                float m = s * invH;
                statsmem[wave * 2] = m;
                statsmem[wave * 2 + 1] = rsqf(q * invH - m * m + 1e-5f);
            }
        }
        bar_lgkm();   // [A] stats visible (lgkm only: gq+xg stay in flight)

        wait_vm1(gq[0], gq[1], gq[2], gq[3]);   // gq ready; xg remains in flight
        float mg[4], rg[4];
        {
            const f32x4* sm = (const f32x4*)statsmem;
            f32x4 s0 = sm[0], s1 = sm[1];
            mg[0] = s0[0]; rg[0] = s0[1]; mg[1] = s0[2]; rg[1] = s0[3];
            mg[2] = s1[0]; rg[2] = s1[1]; mg[3] = s1[2]; rg[3] = s1[3];
        }

        float rcv[4], og4[4];
        float s2 = 0.f, q2 = 0.f;
        #pragma unroll
        for (int j = 0; j < 4; ++j) {
            float li = (gq[0][j] - mg[0]) * rg[0] * ((const float*)&gm[0])[j] + ((const float*)&bt[0])[j];
            float lf = (gq[1][j] - mg[1]) * rg[1] * ((const float*)&gm[1])[j] + ((const float*)&bt[1])[j];
            float lg = (gq[2][j] - mg[2]) * rg[2] * ((const float*)&gm[2])[j] + ((const float*)&bt[2])[j];
            float lo = (gq[3][j] - mg[3]) * rg[3] * ((const float*)&gm[3])[j] + ((const float*)&bt[3])[j];
            float ig = sigf(li);
            float fg = sigf(lf);
            float gg = tanhfast(lg);
            float og = sigf(lo);
            float rv = fg * cprev[j] + ig * gg;
            rcv[j] = rv; og4[j] = og;
            s2 += rv; q2 += rv * rv;
        }
        #pragma unroll
        for (int off = 1; off < 64; off <<= 1) { s2 += __shfl_xor(s2, off); q2 += __shfl_xor(q2, off); }
        if (lane == 0) { red2[wave] = s2; red2[8 + wave] = q2; }
        bar_lgkm();   // [B] cy partials visible

        float mc, rc;
        {
            const f32x4* r4 = (const f32x4*)red2;
            f32x4 sa = r4[0], sb = r4[1], qa = r4[2], qb = r4[3];
            float s = ((sa[0] + sa[1]) + (sa[2] + sa[3])) + ((sb[0] + sb[1]) + (sb[2] + sb[3]));
            float q = ((qa[0] + qa[1]) + (qa[2] + qa[3])) + ((qb[0] + qb[1]) + (qb[2] + qb[3]));
            mc = s * invH;
            rc = rsqf(q * invH - mc * mc + 1e-5f);
        }

        float hvf[4], lcf[4];
        f16x4 hh;
        #pragma unroll
        for (int j = 0; j < 4; ++j) {
            float lc = (rcv[j] - mc) * rc * ((const float*)&gm4)[j] + ((const float*)&bt4)[j];
            cprev[j] = lc;
            float th = tanhfast(lc);
            float hv = og4[j] * th;
            hvf[j] = hv; lcf[j] = lc;
            hh[j] = (_Float16)hv;
        }
        *(f16x4*)&hlds[(t >> 5) * PAD_CH + (p & 127)] = hh;

        if (owner) {   // this block owns global slice [8b, 8b+8)
            float4 ho = {hvf[0], hvf[1], hvf[2], hvf[3]};
            *(float4*)&yout[(size_t)step * HD + p] = ho;
            if (step == SEQ - 1) {
                *(float4*)&hyout[p] = ho;
                float4 co = {lcf[0], lcf[1], lcf[2], lcf[3]};
                *(float4*)&cyout[p] = co;
            }
        }
        bar_lgkm();   // [C] hlds ready for next GEMV
    }
}

extern "C" void kernel_launch(void* const* d_in, const int* in_sizes, int n_in,
                              void* d_out, int out_size, void* d_ws, size_t ws_size,
                              hipStream_t stream) {
    const float* x   = (const float*)d_in[0];
    const float* wih = (const float*)d_in[1];
    const float* whh = (const float*)d_in[2];
    const float* bih = (const float*)d_in[3];
    const float* bhh = (const float*)d_in[4];
    const float* gam = (const float*)d_in[5];
    const float* bet = (const float*)d_in[6];
    float* out = (float*)d_out;

    char* ws = (char*)d_ws;
    size_t off = 0;
    auto carve = [&](size_t bytes) -> void* {
        void* pp = ws + off;
        off += (bytes + 255) & ~(size_t)255;
        return pp;
    };
    float* xg      = (float*)carve(sizeof(float) * (size_t)SEQ * NG);      // 64 MB
    _Float16* whhf = (_Float16*)carve(sizeof(_Float16) * (size_t)NG * HD); // 32 MB
    float* gates   = (float*)carve(sizeof(float) * 2 * NG);
    float* parts   = (float*)carve(sizeof(float) * 2 * NB * 8 * 2);
    unsigned* barctl = (unsigned*)carve(sizeof(unsigned) * 32 * 64);

    cvt_f16_kernel<<<2048, 256, 0, stream>>>(whh, whhf, NG * HD);
    dim3 ggrid(16, 64);
    gemm_xg<<<ggrid, 256, 0, stream>>>(x, wih, bih, bhh, xg);
    hipMemsetAsync(barctl, 0, sizeof(unsigned) * 32 * 64, stream);

    void* args[] = { (void*)&xg, (void*)&whhf, (void*)&gam, (void*)&bet,
                     (void*)&gates, (void*)&parts, (void*)&barctl, (void*)&out };
    hipLaunchCooperativeKernel((void*)lstm_rec, dim3(NB), dim3(NT), args, 0, stream);
}